// Round 2
// 2075.609 us; speedup vs baseline: 1.0788x; 1.0788x over previous
//
#include <hip/hip_runtime.h>
#include <stdint.h>

// ---------------------------------------------------------------------------
// E8RHTLinear: y = fwht(fwht(x*SV)/sqrt(N) @ W^T)/sqrt(M) * SU * Wscale
// Restructured: y = t @ V^T * (SU*Wscale), where
//   t = fwht(x*SV)/64   (bf16, ws)
//   V = fwht_cols(W_hat)/128  (bf16, ws, FWHT-16384 along M as two FWHT-128)
// T=8192, N=4096, M=16384.
//
// R2: resubmission of R1 (container infra failure, no counters). Audited:
// no deadlock (uniform barriers), no OOB, LDS <= 34KB, 16B alignment OK.
//   - fwht_x: radix-16^3, 3 register FWHT-16 stages + 2 LDS transposes
//     (was 12 barrier'd butterfly passes)
//   - decompress fused into colfwht pass 1 (saves 256 MB W1 round-trip)
//   - colfwht: radix 16x8 in registers (F8(a) (x) F16(j)), 64-col tiles
//     so every global row access is a full 128B line
//   - GEMM byte-identical (control)
// ---------------------------------------------------------------------------

typedef __attribute__((ext_vector_type(8)))  __bf16 bf16x8;
typedef __attribute__((ext_vector_type(4)))  float  f32x4;
typedef __attribute__((ext_vector_type(4)))  unsigned short us4;
typedef __attribute__((ext_vector_type(8)))  unsigned short us8;

#define T_ROWS 8192
#define N_DIM  4096
#define M_DIM  16384

__device__ __forceinline__ unsigned short f2bf(float f) {
    unsigned int u = __float_as_uint(f);
    u = (u + 0x7FFFu + ((u >> 16) & 1u)) >> 16;   // RNE
    return (unsigned short)u;
}
__device__ __forceinline__ float bf2f(unsigned short h) {
    return __uint_as_float(((unsigned int)h) << 16);
}

__device__ __forceinline__ void g2l16(const void* g, void* l) {
    __builtin_amdgcn_global_load_lds(
        (const __attribute__((address_space(1))) void*)g,
        (__attribute__((address_space(3))) void*)l,
        16, 0, 0);
}

// In-register FWHT on 16 values (levels h=1,2,4,8) — all indices compile-time.
__device__ __forceinline__ void fwht16(float v[16]) {
#pragma unroll
    for (int h = 1; h < 16; h <<= 1) {
#pragma unroll
        for (int g = 0; g < 16; g += 2 * h) {
#pragma unroll
            for (int k = 0; k < h; ++k) {
                float a = v[g + k], b = v[g + k + h];
                v[g + k]     = a + b;
                v[g + k + h] = a - b;
            }
        }
    }
}

__device__ __forceinline__ void fwht8(float v[8]) {
#pragma unroll
    for (int h = 1; h < 8; h <<= 1) {
#pragma unroll
        for (int g = 0; g < 8; g += 2 * h) {
#pragma unroll
            for (int k = 0; k < h; ++k) {
                float a = v[g + k], b = v[g + k + h];
                v[g + k]     = a + b;
                v[g + k + h] = a - b;
            }
        }
    }
}

// ---------------------------------------------------------------------------
// Kernel 1: t[row] = bf16( fwht(x[row]*SV) / 64 )   one block per row.
// FWHT-4096 = F16(a) (x) F16(b) (x) F16(c), p = a*256 + b*16 + c.
// Stage1: F16 over c (thread t=a*16+b holds x[t*16+c] contiguous).
// Stage2: F16 over b (read s1[c*257 + a*16 + b], contiguous in b).
// Stage3: F16 over a (read s2[(b*16+c)*17 + a], contiguous in a).
// Bank-checked: s1 writes/reads and s2 reads are ~2-way (free); s2 writes
// ~2-3-way. 2 barriers total (was 12).
// ---------------------------------------------------------------------------
__global__ __launch_bounds__(256) void fwht_x_kernel(
    const float* __restrict__ x, const float* __restrict__ SV,
    unsigned short* __restrict__ t)
{
    __shared__ float s1[16 * 257];   // [c][src_thread]
    __shared__ float s2[256 * 17];   // [b*16+c][a]
    const int row = blockIdx.x;
    const int tid = threadIdx.x;
    float v[16];

    const float4* xv  = (const float4*)(x + (size_t)row * N_DIM + tid * 16);
    const float4* svv = (const float4*)(SV + tid * 16);
#pragma unroll
    for (int q = 0; q < 4; ++q) {
        float4 a = xv[q], b = svv[q];
        v[q*4+0] = a.x*b.x; v[q*4+1] = a.y*b.y;
        v[q*4+2] = a.z*b.z; v[q*4+3] = a.w*b.w;
    }
    fwht16(v);                        // transform over c
#pragma unroll
    for (int c = 0; c < 16; ++c) s1[c * 257 + tid] = v[c];
    __syncthreads();

    {   // stage 2: thread = a*16 + c, transform over b
        const int a = tid >> 4, c = tid & 15;
        const float* base = &s1[c * 257 + a * 16];
#pragma unroll
        for (int b = 0; b < 16; ++b) v[b] = base[b];
        fwht16(v);
#pragma unroll
        for (int b = 0; b < 16; ++b) s2[(b * 16 + c) * 17 + a] = v[b];
    }
    __syncthreads();

    {   // stage 3: thread = b*16 + c, transform over a; p = a*256 + tid
        const float* base = &s2[tid * 17];
#pragma unroll
        for (int a = 0; a < 16; ++a) v[a] = base[a];
        fwht16(v);
        const float sc = 1.0f / 64.0f;   // 1/sqrt(4096)
        unsigned short* out = t + (size_t)row * N_DIM + tid;
#pragma unroll
        for (int a = 0; a < 16; ++a) out[a * 256] = f2bf(v[a] * sc);
    }
}

// ---------------------------------------------------------------------------
// Shared FWHT-128 over the row index r of a 128(rows) x 64(cols) LDS tile,
// layout s[c*129 + r].  r = a*16 + j:  stage A = F16 over j (contiguous,
// per-slot-private 16 elems), stage B = F8 over a (stride-16).  All LDS
// accesses verified ~2-way (free). Caller barriers before entry.
// ---------------------------------------------------------------------------
__device__ __forceinline__ void fwht128_tile(float* __restrict__ s, int tid)
{
    // stage A: 512 slots (c,a), 2 per thread
#pragma unroll
    for (int k = 0; k < 2; ++k) {
        int sA = tid + k * 256;
        int c = sA & 63, a = sA >> 6;
        float* base = s + c * 129 + a * 16;
        float v[16];
#pragma unroll
        for (int j = 0; j < 16; ++j) v[j] = base[j];
        fwht16(v);
#pragma unroll
        for (int j = 0; j < 16; ++j) base[j] = v[j];
    }
    __syncthreads();
    // stage B: 1024 slots (c,j), 4 per thread
#pragma unroll
    for (int k = 0; k < 4; ++k) {
        int sB = tid + k * 256;
        int c = sB & 63, j = sB >> 6;
        float* base = s + c * 129 + j;
        float v[8];
#pragma unroll
        for (int a = 0; a < 8; ++a) v[a] = base[a * 16];
        fwht8(v);
#pragma unroll
        for (int a = 0; a < 8; ++a) base[a * 16] = v[a];
    }
    __syncthreads();
}

// ---------------------------------------------------------------------------
// Kernel 2: fused decompress + FWHT-128 over contiguous rows (pass 1).
// Block = 128 rows (m = grp*128 + r) x 64 cols (n = nt*64 .. +64).
// Decompress straight into the LDS tile (skips the 128MB W1 write + re-read
// and one intermediate bf16 rounding).
// grid = (64 col-tiles [x, fast-varying -> index-line L2 reuse], 128 groups)
// ---------------------------------------------------------------------------
__global__ __launch_bounds__(256) void dec_fwht_kernel(
    const int* __restrict__ Qidxs, const int* __restrict__ Qidxs2,
    const float* __restrict__ cb, const float* __restrict__ cb2,
    const float* __restrict__ inv_resid_scale,
    unsigned short* __restrict__ W)
{
    __shared__ float s[64 * 129];
    const int nt  = blockIdx.x;
    const int grp = blockIdx.y;
    const int tid = threadIdx.x;
    const float irs = inv_resid_scale[0];

    // fill: 1024 slots (r, e), e = 8-col codebook entry
#pragma unroll
    for (int k = 0; k < 4; ++k) {
        int slot = tid + k * 256;
        int r = slot >> 3, e = slot & 7;
        size_t m = (size_t)grp * 128 + r;
        size_t q = m * (N_DIM / 8) + nt * 8 + e;
        int i1 = Qidxs[q], i2 = Qidxs2[q];
        const float4* c1 = (const float4*)(cb  + (size_t)i1 * 8);
        const float4* c2 = (const float4*)(cb2 + (size_t)i2 * 8);
        float4 a0 = c1[0], a1 = c1[1], b0 = c2[0], b1 = c2[1];
        float* col = s + (e * 8) * 129 + r;
        col[0 * 129] = a0.x + irs * b0.x;
        col[1 * 129] = a0.y + irs * b0.y;
        col[2 * 129] = a0.z + irs * b0.z;
        col[3 * 129] = a0.w + irs * b0.w;
        col[4 * 129] = a1.x + irs * b1.x;
        col[5 * 129] = a1.y + irs * b1.y;
        col[6 * 129] = a1.z + irs * b1.z;
        col[7 * 129] = a1.w + irs * b1.w;
    }
    __syncthreads();

    fwht128_tile(s, tid);

    // store bf16, 16B per slot, 128B contiguous per 8 threads
#pragma unroll
    for (int k = 0; k < 4; ++k) {
        int slot = tid + k * 256;
        int r = slot >> 3, e = slot & 7;
        size_t m = (size_t)grp * 128 + r;
        const float* col = s + (e * 8) * 129 + r;
        us8 o;
#pragma unroll
        for (int j = 0; j < 8; ++j) o[j] = f2bf(col[j * 129]);
        *(us8*)(W + m * N_DIM + nt * 64 + e * 8) = o;
    }
}

// ---------------------------------------------------------------------------
// Kernel 3: FWHT-128 over strided rows (pass 2), m = grp + 128*r, scale 1/128.
// 64-col tiles -> each row access is a full 128B line (was 64B).
// ---------------------------------------------------------------------------
__global__ __launch_bounds__(256) void colfwht2_kernel(
    unsigned short* __restrict__ W)
{
    __shared__ float s[64 * 129];
    const int nt  = blockIdx.x;
    const int grp = blockIdx.y;
    const int tid = threadIdx.x;

#pragma unroll
    for (int k = 0; k < 4; ++k) {
        int slot = tid + k * 256;
        int r = slot >> 3, e = slot & 7;
        size_t m = (size_t)grp + (size_t)r * 128;
        us8 v = *(const us8*)(W + m * N_DIM + nt * 64 + e * 8);
        float* col = s + (e * 8) * 129 + r;
#pragma unroll
        for (int j = 0; j < 8; ++j) col[j * 129] = bf2f(v[j]);
    }
    __syncthreads();

    fwht128_tile(s, tid);

    const float sc = 1.0f / 128.0f;   // 1/sqrt(16384)
#pragma unroll
    for (int k = 0; k < 4; ++k) {
        int slot = tid + k * 256;
        int r = slot >> 3, e = slot & 7;
        size_t m = (size_t)grp + (size_t)r * 128;
        const float* col = s + (e * 8) * 129 + r;
        us8 o;
#pragma unroll
        for (int j = 0; j < 8; ++j) o[j] = f2bf(col[j * 129] * sc);
        *(us8*)(W + m * N_DIM + nt * 64 + e * 8) = o;
    }
}

// ---------------------------------------------------------------------------
// Kernel 4: GEMM  Y[i][j] = (SU[j]*Wscale) * sum_k t[i][k] * V[j][k]
// 128x128 block tile, BK=32, 4 waves (2x2), each wave 4x4 of 16x16x32 MFMA.
// global_load_lds width-16 staging (m97 structure). UNCHANGED (control).
// ---------------------------------------------------------------------------
__global__ __launch_bounds__(256) void gemm_kernel(
    const unsigned short* __restrict__ A,   // t: T_ROWS x N_DIM (bf16 bits)
    const unsigned short* __restrict__ B,   // V: M_DIM  x N_DIM (bf16 bits)
    const float* __restrict__ SU,
    const float* __restrict__ Wscale,
    float* __restrict__ Y)
{
    __shared__ unsigned short As[128 * 32];
    __shared__ unsigned short Bs[128 * 32];

    const int tid  = threadIdx.x;
    const int lane = tid & 63;
    const int w    = tid >> 6;
    const int wm   = w & 1;
    const int wn   = w >> 1;
    const int i0   = blockIdx.x * 128;
    const int j0   = blockIdx.y * 128;

    f32x4 acc[4][4] = {};

    const int lrow = lane >> 2;        // 0..15: row within 16-row chunk
    const int lc8  = (lane & 3) * 8;   // 0,8,16,24: k-offset

    for (int k0 = 0; k0 < N_DIM; k0 += 32) {
        __syncthreads();
#pragma unroll
        for (int q = 0; q < 2; ++q) {
            const int rr = w * 32 + q * 16;          // wave-uniform chunk base
            const unsigned short* ga =
                A + (size_t)(i0 + rr + lrow) * N_DIM + k0 + lc8;
            g2l16(ga, &As[rr * 32]);
            const unsigned short* gb =
                B + (size_t)(j0 + rr + lrow) * N_DIM + k0 + lc8;
            g2l16(gb, &Bs[rr * 32]);
        }
        __syncthreads();

        const int k8   = (lane >> 4) * 8;  // 0,8,16,24
        const int mrow = lane & 15;
        bf16x8 af[4], bfr[4];
#pragma unroll
        for (int tm = 0; tm < 4; ++tm)
            af[tm] = *(const bf16x8*)&As[(wm * 64 + tm * 16 + mrow) * 32 + k8];
#pragma unroll
        for (int tn = 0; tn < 4; ++tn)
            bfr[tn] = *(const bf16x8*)&Bs[(wn * 64 + tn * 16 + mrow) * 32 + k8];
#pragma unroll
        for (int tm = 0; tm < 4; ++tm)
#pragma unroll
            for (int tn = 0; tn < 4; ++tn)
                acc[tm][tn] = __builtin_amdgcn_mfma_f32_16x16x32_bf16(
                    af[tm], bfr[tn], acc[tm][tn], 0, 0, 0);
    }

    // epilogue: C/D layout col=lane&15, row=(lane>>4)*4+reg
    const float wsc  = Wscale[0];
    const int ccol  = lane & 15;
    const int crow4 = (lane >> 4) * 4;
#pragma unroll
    for (int tn = 0; tn < 4; ++tn) {
        const int col = j0 + wn * 64 + tn * 16 + ccol;
        const float su = SU[col] * wsc;
#pragma unroll
        for (int tm = 0; tm < 4; ++tm) {
            const int rowb = i0 + wm * 64 + tm * 16 + crow4;
#pragma unroll
            for (int r = 0; r < 4; ++r)
                Y[(size_t)(rowb + r) * M_DIM + col] = acc[tm][tn][r] * su;
        }
    }
}

// ---------------------------------------------------------------------------
extern "C" void kernel_launch(void* const* d_in, const int* in_sizes, int n_in,
                              void* d_out, int out_size, void* d_ws, size_t ws_size,
                              hipStream_t stream) {
    const float* x       = (const float*)d_in[0];
    const int*   Qidxs   = (const int*)  d_in[1];
    const int*   Qidxs2  = (const int*)  d_in[2];
    const float* SU      = (const float*)d_in[3];
    const float* SV      = (const float*)d_in[4];
    const float* cb      = (const float*)d_in[5];
    const float* cb2     = (const float*)d_in[6];
    const float* Wscale  = (const float*)d_in[7];
    const float* irs     = (const float*)d_in[8];
    float*       y       = (float*)d_out;

    char* ws = (char*)d_ws;
    unsigned short* t  = (unsigned short*)ws;                        // 64 MB
    unsigned short* W1 = (unsigned short*)(ws + ((size_t)64 << 20)); // 128 MB

    // t = fwht(x*SV)/64
    fwht_x_kernel<<<T_ROWS, 256, 0, stream>>>(x, SV, t);
    // W1 = fwht-128 over contiguous rows of decompressed W_hat (fused)
    dec_fwht_kernel<<<dim3(N_DIM / 64, M_DIM / 128), 256, 0, stream>>>(
        Qidxs, Qidxs2, cb, cb2, irs, W1);
    // W1 = fwht-128 over stride-128 rows, scale 1/128  (completes FWHT-16384)
    colfwht2_kernel<<<dim3(N_DIM / 64, M_DIM / 128), 256, 0, stream>>>(W1);
    // y = t @ V^T * SU * Wscale
    gemm_kernel<<<dim3(T_ROWS / 128, M_DIM / 128), 256, 0, stream>>>(
        t, W1, SU, Wscale, y);
}

// Round 3
// 1747.610 us; speedup vs baseline: 1.2813x; 1.1877x over previous
//
#include <hip/hip_runtime.h>
#include <stdint.h>

// ---------------------------------------------------------------------------
// E8RHTLinear: y = fwht(fwht(x*SV)/sqrt(N) @ W^T)/sqrt(M) * SU * Wscale
// Restructured: y = t @ V^T * (SU*Wscale), where
//   t = fwht(x*SV)/64   (bf16, ws)
//   V = fwht_cols(W_hat)/128  (bf16, ws, FWHT-16384 along M as two FWHT-128)
// T=8192, N=4096, M=16384.
//
// R3: GEMM v3 — 256x256 tile, BK=64, 8 waves, 4-phase/K-tile schedule with
// counted vmcnt (T3+T4), LDS XOR swizzle (T2), setprio (T5). Prep kernels
// unchanged (control).
//
// GEMM schedule (group = K-tile kt, buffer p=kt&1, 4 phases):
//   ph1: read A-k0 x8 + B-k0 nf{0,1}; stage A-k1(kt+1)->buf(1-p);  16 MFMA kk0
//   ph2: read B-k0 nf{2,3} + A-k1 mf{0..3}; stage B-k1(kt+1);      16 MFMA kk0
//   ph3: read A-k1 mf{4..7} + B-k1 nf{0,1}; stage A-k0(kt+2)->buf(p); 16 MFMA kk1
//   ph4: read B-k1 nf{2,3}; stage B-k0(kt+2); vmcnt(4); 16 MFMA kk1
// Safety: a slot staged in phase X was last read >=2 barriers earlier; boundary
// vmcnt(4) leaves only k0(kt+2) in flight and guarantees tile kt+1 arrived.
// Swizzle: LDS granule G(r,kg) = r*4 + (kg ^ ((r>>1)&3)) (involution), applied
// to the global SOURCE at stage (linear global_load_lds dest) and to the read
// address -> fragment reads hit all 8 bank-groups (2-way, free).
// ---------------------------------------------------------------------------

typedef __attribute__((ext_vector_type(8)))  __bf16 bf16x8;
typedef __attribute__((ext_vector_type(4)))  float  f32x4;
typedef __attribute__((ext_vector_type(4)))  unsigned short us4;
typedef __attribute__((ext_vector_type(8)))  unsigned short us8;

#define T_ROWS 8192
#define N_DIM  4096
#define M_DIM  16384
#define NT_TILES 64   // N_DIM / 64

__device__ __forceinline__ unsigned short f2bf(float f) {
    unsigned int u = __float_as_uint(f);
    u = (u + 0x7FFFu + ((u >> 16) & 1u)) >> 16;   // RNE
    return (unsigned short)u;
}
__device__ __forceinline__ float bf2f(unsigned short h) {
    return __uint_as_float(((unsigned int)h) << 16);
}

__device__ __forceinline__ void g2l16(const void* g, void* l) {
    __builtin_amdgcn_global_load_lds(
        (const __attribute__((address_space(1))) void*)g,
        (__attribute__((address_space(3))) void*)l,
        16, 0, 0);
}

// In-register FWHT on 16 values (levels h=1,2,4,8) — all indices compile-time.
__device__ __forceinline__ void fwht16(float v[16]) {
#pragma unroll
    for (int h = 1; h < 16; h <<= 1) {
#pragma unroll
        for (int g = 0; g < 16; g += 2 * h) {
#pragma unroll
            for (int k = 0; k < h; ++k) {
                float a = v[g + k], b = v[g + k + h];
                v[g + k]     = a + b;
                v[g + k + h] = a - b;
            }
        }
    }
}

__device__ __forceinline__ void fwht8(float v[8]) {
#pragma unroll
    for (int h = 1; h < 8; h <<= 1) {
#pragma unroll
        for (int g = 0; g < 8; g += 2 * h) {
#pragma unroll
            for (int k = 0; k < h; ++k) {
                float a = v[g + k], b = v[g + k + h];
                v[g + k]     = a + b;
                v[g + k + h] = a - b;
            }
        }
    }
}

// ---------------------------------------------------------------------------
// Kernel 1: t[row] = bf16( fwht(x[row]*SV) / 64 )   one block per row.
// ---------------------------------------------------------------------------
__global__ __launch_bounds__(256) void fwht_x_kernel(
    const float* __restrict__ x, const float* __restrict__ SV,
    unsigned short* __restrict__ t)
{
    __shared__ float s1[16 * 257];   // [c][src_thread]
    __shared__ float s2[256 * 17];   // [b*16+c][a]
    const int row = blockIdx.x;
    const int tid = threadIdx.x;
    float v[16];

    const float4* xv  = (const float4*)(x + (size_t)row * N_DIM + tid * 16);
    const float4* svv = (const float4*)(SV + tid * 16);
#pragma unroll
    for (int q = 0; q < 4; ++q) {
        float4 a = xv[q], b = svv[q];
        v[q*4+0] = a.x*b.x; v[q*4+1] = a.y*b.y;
        v[q*4+2] = a.z*b.z; v[q*4+3] = a.w*b.w;
    }
    fwht16(v);                        // transform over c
#pragma unroll
    for (int c = 0; c < 16; ++c) s1[c * 257 + tid] = v[c];
    __syncthreads();

    {   // stage 2: thread = a*16 + c, transform over b
        const int a = tid >> 4, c = tid & 15;
        const float* base = &s1[c * 257 + a * 16];
#pragma unroll
        for (int b = 0; b < 16; ++b) v[b] = base[b];
        fwht16(v);
#pragma unroll
        for (int b = 0; b < 16; ++b) s2[(b * 16 + c) * 17 + a] = v[b];
    }
    __syncthreads();

    {   // stage 3: thread = b*16 + c, transform over a; p = a*256 + tid
        const float* base = &s2[tid * 17];
#pragma unroll
        for (int a = 0; a < 16; ++a) v[a] = base[a];
        fwht16(v);
        const float sc = 1.0f / 64.0f;   // 1/sqrt(4096)
        unsigned short* out = t + (size_t)row * N_DIM + tid;
#pragma unroll
        for (int a = 0; a < 16; ++a) out[a * 256] = f2bf(v[a] * sc);
    }
}

// ---------------------------------------------------------------------------
// Shared FWHT-128 over rows of a 128x64 LDS tile, layout s[c*129 + r].
// ---------------------------------------------------------------------------
__device__ __forceinline__ void fwht128_tile(float* __restrict__ s, int tid)
{
    // stage A: 512 slots (c,a), 2 per thread
#pragma unroll
    for (int k = 0; k < 2; ++k) {
        int sA = tid + k * 256;
        int c = sA & 63, a = sA >> 6;
        float* base = s + c * 129 + a * 16;
        float v[16];
#pragma unroll
        for (int j = 0; j < 16; ++j) v[j] = base[j];
        fwht16(v);
#pragma unroll
        for (int j = 0; j < 16; ++j) base[j] = v[j];
    }
    __syncthreads();
    // stage B: 1024 slots (c,j), 4 per thread
#pragma unroll
    for (int k = 0; k < 4; ++k) {
        int sB = tid + k * 256;
        int c = sB & 63, j = sB >> 6;
        float* base = s + c * 129 + j;
        float v[8];
#pragma unroll
        for (int a = 0; a < 8; ++a) v[a] = base[a * 16];
        fwht8(v);
#pragma unroll
        for (int a = 0; a < 8; ++a) base[a * 16] = v[a];
    }
    __syncthreads();
}

// ---------------------------------------------------------------------------
// Kernel 2: fused decompress + FWHT-128 over contiguous rows (pass 1).
// ---------------------------------------------------------------------------
__global__ __launch_bounds__(256) void dec_fwht_kernel(
    const int* __restrict__ Qidxs, const int* __restrict__ Qidxs2,
    const float* __restrict__ cb, const float* __restrict__ cb2,
    const float* __restrict__ inv_resid_scale,
    unsigned short* __restrict__ W)
{
    __shared__ float s[64 * 129];
    const int nt  = blockIdx.x;
    const int grp = blockIdx.y;
    const int tid = threadIdx.x;
    const float irs = inv_resid_scale[0];

#pragma unroll
    for (int k = 0; k < 4; ++k) {
        int slot = tid + k * 256;
        int r = slot >> 3, e = slot & 7;
        size_t m = (size_t)grp * 128 + r;
        size_t q = m * (N_DIM / 8) + nt * 8 + e;
        int i1 = Qidxs[q], i2 = Qidxs2[q];
        const float4* c1 = (const float4*)(cb  + (size_t)i1 * 8);
        const float4* c2 = (const float4*)(cb2 + (size_t)i2 * 8);
        float4 a0 = c1[0], a1 = c1[1], b0 = c2[0], b1 = c2[1];
        float* col = s + (e * 8) * 129 + r;
        col[0 * 129] = a0.x + irs * b0.x;
        col[1 * 129] = a0.y + irs * b0.y;
        col[2 * 129] = a0.z + irs * b0.z;
        col[3 * 129] = a0.w + irs * b0.w;
        col[4 * 129] = a1.x + irs * b1.x;
        col[5 * 129] = a1.y + irs * b1.y;
        col[6 * 129] = a1.z + irs * b1.z;
        col[7 * 129] = a1.w + irs * b1.w;
    }
    __syncthreads();

    fwht128_tile(s, tid);

#pragma unroll
    for (int k = 0; k < 4; ++k) {
        int slot = tid + k * 256;
        int r = slot >> 3, e = slot & 7;
        size_t m = (size_t)grp * 128 + r;
        const float* col = s + (e * 8) * 129 + r;
        us8 o;
#pragma unroll
        for (int j = 0; j < 8; ++j) o[j] = f2bf(col[j * 129]);
        *(us8*)(W + m * N_DIM + nt * 64 + e * 8) = o;
    }
}

// ---------------------------------------------------------------------------
// Kernel 3: FWHT-128 over strided rows (pass 2), m = grp + 128*r, scale 1/128.
// ---------------------------------------------------------------------------
__global__ __launch_bounds__(256) void colfwht2_kernel(
    unsigned short* __restrict__ W)
{
    __shared__ float s[64 * 129];
    const int nt  = blockIdx.x;
    const int grp = blockIdx.y;
    const int tid = threadIdx.x;

#pragma unroll
    for (int k = 0; k < 4; ++k) {
        int slot = tid + k * 256;
        int r = slot >> 3, e = slot & 7;
        size_t m = (size_t)grp + (size_t)r * 128;
        us8 v = *(const us8*)(W + m * N_DIM + nt * 64 + e * 8);
        float* col = s + (e * 8) * 129 + r;
#pragma unroll
        for (int j = 0; j < 8; ++j) col[j * 129] = bf2f(v[j]);
    }
    __syncthreads();

    fwht128_tile(s, tid);

    const float sc = 1.0f / 128.0f;   // 1/sqrt(16384)
#pragma unroll
    for (int k = 0; k < 4; ++k) {
        int slot = tid + k * 256;
        int r = slot >> 3, e = slot & 7;
        size_t m = (size_t)grp + (size_t)r * 128;
        const float* col = s + (e * 8) * 129 + r;
        us8 o;
#pragma unroll
        for (int j = 0; j < 8; ++j) o[j] = f2bf(col[j * 129] * sc);
        *(us8*)(W + m * N_DIM + nt * 64 + e * 8) = o;
    }
}

// ---------------------------------------------------------------------------
// Kernel 4 (v3): GEMM  Y[i][j] = (SU[j]*Wscale) * sum_k t[i][k] * V[j][k]
// 256x256 tile, BK=64, 512 threads / 8 waves (2m x 4n), wave tile 128x64.
// Phase-interleaved schedule with counted vmcnt; see header comment.
// LDS slots (bytes): slot(p,M,h) = p*65536 + M*32768 + h*16384, each 16KB
// holding 256 rows x 32 k-cols bf16 as granules G(r,kg)=r*4+(kg^((r>>1)&3)).
// ---------------------------------------------------------------------------
__global__ __launch_bounds__(512, 2) void gemm_kernel(
    const unsigned short* __restrict__ A,   // t: T_ROWS x N_DIM (bf16 bits)
    const unsigned short* __restrict__ B,   // V: M_DIM  x N_DIM (bf16 bits)
    const float* __restrict__ SU,
    const float* __restrict__ Wscale,
    float* __restrict__ Y)
{
    __shared__ unsigned short lds[65536];   // 128 KB
    char* ldsc = (char*)lds;

    const int tid  = threadIdx.x;
    const int lane = tid & 63;
    const int w    = tid >> 6;     // 0..7
    const int wm   = w >> 2;       // 0..1 : row half
    const int wn   = w & 3;        // 0..3 : col quarter
    const int i0   = blockIdx.x * 256;
    const int j0   = blockIdx.y * 256;

    // ---- per-thread fragment-read bases (swizzled) ----
    const int kgl = lane >> 4;             // 0..3 : k-granule within khalf
    const int lr  = lane & 15;             // row within 16-row fragment
    const int rA0 = wm * 128 + lr;
    const int rB0 = wn * 64  + lr;
    const int baseA = rA0 * 64 + (kgl ^ ((rA0 >> 1) & 3)) * 16;  // bytes in slot
    const int baseB = rB0 * 64 + (kgl ^ ((rB0 >> 1) & 3)) * 16;

    // ---- per-thread staging addresses ----
    // granule G = q*512 + w*64 + lane; r=G>>2; kg=(G&3)^((r>>1)&3)
    const int G0  = w * 64 + lane;
    const int G1  = G0 + 512;
    const int r0g = G0 >> 2, r1g = G1 >> 2;
    const int kg0 = (G0 & 3) ^ ((r0g >> 1) & 3);
    const int kg1 = (G1 & 3) ^ ((r1g >> 1) & 3);
    const unsigned short* Asrc0 = A + (size_t)(i0 + r0g) * N_DIM + kg0 * 8;
    const unsigned short* Asrc1 = A + (size_t)(i0 + r1g) * N_DIM + kg1 * 8;
    const unsigned short* Bsrc0 = B + (size_t)(j0 + r0g) * N_DIM + kg0 * 8;
    const unsigned short* Bsrc1 = B + (size_t)(j0 + r1g) * N_DIM + kg1 * 8;
    const int ldst0 = G0 * 16 - lane * 16;   // wave-uniform LDS base, q=0
    const int ldst1 = ldst0 + 8192;          // q=1

    f32x4 acc[8][4] = {};

    // ---- prologue: stage tile0 (h0,h1) + tile1 h0 ----
    g2l16(Asrc0 +  0, ldsc + 0             + ldst0);
    g2l16(Asrc1 +  0, ldsc + 0             + ldst1);
    g2l16(Bsrc0 +  0, ldsc + 32768         + ldst0);
    g2l16(Bsrc1 +  0, ldsc + 32768         + ldst1);
    g2l16(Asrc0 + 32, ldsc + 16384         + ldst0);
    g2l16(Asrc1 + 32, ldsc + 16384         + ldst1);
    g2l16(Bsrc0 + 32, ldsc + 32768 + 16384 + ldst0);
    g2l16(Bsrc1 + 32, ldsc + 32768 + 16384 + ldst1);
    g2l16(Asrc0 + 64, ldsc + 65536         + ldst0);
    g2l16(Asrc1 + 64, ldsc + 65536         + ldst1);
    g2l16(Bsrc0 + 64, ldsc + 65536 + 32768 + ldst0);
    g2l16(Bsrc1 + 64, ldsc + 65536 + 32768 + ldst1);
    asm volatile("s_waitcnt vmcnt(4)" ::: "memory");   // tile0 fully arrived
    __builtin_amdgcn_s_barrier();

    // ---- main loop: one 4-phase group per K-tile ----
#pragma unroll 1
    for (int ktp = 0; ktp < NT_TILES; ktp += 2) {
#pragma unroll
        for (int p = 0; p < 2; ++p) {
            const int  kt  = ktp + p;
            const int  k0  = kt * 64;
            const int  sp  = p * 65536;          // this tile's buffer
            const int  so  = (1 - p) * 65536;    // other buffer
            const bool st1 = (kt + 1) < NT_TILES;
            const bool st2 = (kt + 2) < NT_TILES;

            bf16x8 a[8], c[8], b0, b1, b2, b3, d0, d1, d2, d3;

            // ---------- phase 1: A-k0 x8, B-k0 nf{0,1}; stage A-k1(kt+1) ----
#pragma unroll
            for (int mf = 0; mf < 8; ++mf)
                a[mf] = *(const bf16x8*)(ldsc + sp + baseA + mf * 1024);
            b0 = *(const bf16x8*)(ldsc + sp + 32768 + baseB + 0 * 1024);
            b1 = *(const bf16x8*)(ldsc + sp + 32768 + baseB + 1 * 1024);
            if (st1) {
                g2l16(Asrc0 + k0 + 96, ldsc + so + 16384 + ldst0);
                g2l16(Asrc1 + k0 + 96, ldsc + so + 16384 + ldst1);
            }
            __builtin_amdgcn_s_barrier();
            __builtin_amdgcn_s_setprio(1);
#pragma unroll
            for (int mf = 0; mf < 8; ++mf) {
                acc[mf][0] = __builtin_amdgcn_mfma_f32_16x16x32_bf16(a[mf], b0, acc[mf][0], 0, 0, 0);
                acc[mf][1] = __builtin_amdgcn_mfma_f32_16x16x32_bf16(a[mf], b1, acc[mf][1], 0, 0, 0);
            }
            __builtin_amdgcn_s_setprio(0);
            __builtin_amdgcn_s_barrier();

            // ---------- phase 2: B-k0 nf{2,3}, A-k1 mf{0..3}; stage B-k1 ----
            b2 = *(const bf16x8*)(ldsc + sp + 32768 + baseB + 2 * 1024);
            b3 = *(const bf16x8*)(ldsc + sp + 32768 + baseB + 3 * 1024);
#pragma unroll
            for (int mf = 0; mf < 4; ++mf)
                c[mf] = *(const bf16x8*)(ldsc + sp + 16384 + baseA + mf * 1024);
            if (st1) {
                g2l16(Bsrc0 + k0 + 96, ldsc + so + 32768 + 16384 + ldst0);
                g2l16(Bsrc1 + k0 + 96, ldsc + so + 32768 + 16384 + ldst1);
            }
            __builtin_amdgcn_s_barrier();
            __builtin_amdgcn_s_setprio(1);
#pragma unroll
            for (int mf = 0; mf < 8; ++mf) {
                acc[mf][2] = __builtin_amdgcn_mfma_f32_16x16x32_bf16(a[mf], b2, acc[mf][2], 0, 0, 0);
                acc[mf][3] = __builtin_amdgcn_mfma_f32_16x16x32_bf16(a[mf], b3, acc[mf][3], 0, 0, 0);
            }
            __builtin_amdgcn_s_setprio(0);
            __builtin_amdgcn_s_barrier();

            // ---------- phase 3: A-k1 mf{4..7}, B-k1 nf{0,1}; stage A-k0(kt+2)
#pragma unroll
            for (int mf = 4; mf < 8; ++mf)
                c[mf] = *(const bf16x8*)(ldsc + sp + 16384 + baseA + mf * 1024);
            d0 = *(const bf16x8*)(ldsc + sp + 32768 + 16384 + baseB + 0 * 1024);
            d1 = *(const bf16x8*)(ldsc + sp + 32768 + 16384 + baseB + 1 * 1024);
            if (st2) {
                g2l16(Asrc0 + k0 + 128, ldsc + sp + ldst0);
                g2l16(Asrc1 + k0 + 128, ldsc + sp + ldst1);
            }
            __builtin_amdgcn_s_barrier();
            __builtin_amdgcn_s_setprio(1);
#pragma unroll
            for (int mf = 0; mf < 8; ++mf) {
                acc[mf][0] = __builtin_amdgcn_mfma_f32_16x16x32_bf16(c[mf], d0, acc[mf][0], 0, 0, 0);
                acc[mf][1] = __builtin_amdgcn_mfma_f32_16x16x32_bf16(c[mf], d1, acc[mf][1], 0, 0, 0);
            }
            __builtin_amdgcn_s_setprio(0);
            __builtin_amdgcn_s_barrier();

            // ---------- phase 4: B-k1 nf{2,3}; stage B-k0(kt+2); vmcnt ------
            d2 = *(const bf16x8*)(ldsc + sp + 32768 + 16384 + baseB + 2 * 1024);
            d3 = *(const bf16x8*)(ldsc + sp + 32768 + 16384 + baseB + 3 * 1024);
            if (st2) {
                g2l16(Bsrc0 + k0 + 128, ldsc + sp + 32768 + ldst0);
                g2l16(Bsrc1 + k0 + 128, ldsc + sp + 32768 + ldst1);
                asm volatile("s_waitcnt vmcnt(4)" ::: "memory");
            } else {
                asm volatile("s_waitcnt vmcnt(0)" ::: "memory");
            }
            __builtin_amdgcn_s_barrier();
            __builtin_amdgcn_s_setprio(1);
#pragma unroll
            for (int mf = 0; mf < 8; ++mf) {
                acc[mf][2] = __builtin_amdgcn_mfma_f32_16x16x32_bf16(c[mf], d2, acc[mf][2], 0, 0, 0);
                acc[mf][3] = __builtin_amdgcn_mfma_f32_16x16x32_bf16(c[mf], d3, acc[mf][3], 0, 0, 0);
            }
            __builtin_amdgcn_s_setprio(0);
            __builtin_amdgcn_s_barrier();
        }
    }

    // ---- epilogue: C/D layout col=lane&15, row=(lane>>4)*4+r ----
    const float wsc  = Wscale[0];
    const int ccol   = lane & 15;
    const int crow4  = (lane >> 4) * 4;
#pragma unroll
    for (int nf = 0; nf < 4; ++nf) {
        const int col = j0 + wn * 64 + nf * 16 + ccol;
        const float su = SU[col] * wsc;
#pragma unroll
        for (int mf = 0; mf < 8; ++mf) {
            const int rowb = i0 + wm * 128 + mf * 16 + crow4;
#pragma unroll
            for (int r = 0; r < 4; ++r)
                Y[(size_t)(rowb + r) * M_DIM + col] = acc[mf][nf][r] * su;
        }
    }
}

// ---------------------------------------------------------------------------
extern "C" void kernel_launch(void* const* d_in, const int* in_sizes, int n_in,
                              void* d_out, int out_size, void* d_ws, size_t ws_size,
                              hipStream_t stream) {
    const float* x       = (const float*)d_in[0];
    const int*   Qidxs   = (const int*)  d_in[1];
    const int*   Qidxs2  = (const int*)  d_in[2];
    const float* SU      = (const float*)d_in[3];
    const float* SV      = (const float*)d_in[4];
    const float* cb      = (const float*)d_in[5];
    const float* cb2     = (const float*)d_in[6];
    const float* Wscale  = (const float*)d_in[7];
    const float* irs     = (const float*)d_in[8];
    float*       y       = (float*)d_out;

    char* ws = (char*)d_ws;
    unsigned short* t  = (unsigned short*)ws;                        // 64 MB
    unsigned short* W1 = (unsigned short*)(ws + ((size_t)64 << 20)); // 128 MB

    // t = fwht(x*SV)/64
    fwht_x_kernel<<<T_ROWS, 256, 0, stream>>>(x, SV, t);
    // W1 = fwht-128 over contiguous rows of decompressed W_hat (fused)
    dec_fwht_kernel<<<dim3(N_DIM / 64, M_DIM / 128), 256, 0, stream>>>(
        Qidxs, Qidxs2, cb, cb2, irs, W1);
    // W1 = fwht-128 over stride-128 rows, scale 1/128  (completes FWHT-16384)
    colfwht2_kernel<<<dim3(N_DIM / 64, M_DIM / 128), 256, 0, stream>>>(W1);
    // y = t @ V^T * SU * Wscale
    gemm_kernel<<<dim3(T_ROWS / 256, M_DIM / 256), 512, 0, stream>>>(
        t, W1, SU, Wscale, y);
}